// Round 1
// baseline (1537.558 us; speedup 1.0000x reference)
//
#include <hip/hip_runtime.h>

#define N_IN   1000000
#define N_OUT  250000
#define KOFF   8
#define PPAIR  125000
#define C_IN   64
#define C_OUT  128
#define BN_EPS 1e-5f

// ---------------------------------------------------------------------------
// Kernel 1: gather-GEMM-scatter.
// One wave (64 lanes) per indice pair. Lane L computes output channels L and
// L+64. The 64-float feature row is loaded one element per lane and broadcast
// with __shfl. Weights for offset k are read coalesced (64 lanes x 4B = 256B
// per load) and stay hot in L1/L2 (32 KB per offset, 256 KB total).
// Scatter via per-lane fp32 atomicAdd (addresses coalesced within the wave).
// ---------------------------------------------------------------------------
__global__ __launch_bounds__(256) void scatter_gemm(
    const float* __restrict__ feat,
    const float* __restrict__ weight,
    const int*   __restrict__ in_idx,
    const int*   __restrict__ out_idx,
    float*       __restrict__ out)
{
    const int lane = threadIdx.x & 63;
    const int wave = threadIdx.x >> 6;                 // 0..3
    const int k    = blockIdx.y;                       // kernel offset
    const int p    = blockIdx.x * 4 + wave;            // pair within offset
    if (p >= PPAIR) return;

    const int pair = k * PPAIR + p;
    const int iidx = in_idx[pair];
    const int oidx = out_idx[pair];

    const float f = feat[(long)iidx * C_IN + lane];    // coalesced 256B row
    const float* __restrict__ W = weight + (long)k * (C_IN * C_OUT);

    float acc0 = 0.f, acc1 = 0.f;
#pragma unroll
    for (int i = 0; i < C_IN; ++i) {
        const float fi = __shfl(f, i, 64);
        acc0 = fmaf(fi, W[i * C_OUT + lane],      acc0);
        acc1 = fmaf(fi, W[i * C_OUT + lane + 64], acc1);
    }

    float* orow = out + (long)oidx * C_OUT;
    atomicAdd(orow + lane,      acc0);
    atomicAdd(orow + lane + 64, acc1);
}

// ---------------------------------------------------------------------------
// Kernel 2: per-channel sum and sum-of-squares.
// Block = 512 threads: channel = tid&127, row-group = tid>>7 (4 rows/iter).
// LDS reduce across row-groups, one atomicAdd pair per channel per block.
// ---------------------------------------------------------------------------
__global__ __launch_bounds__(512) void bn_stats(
    const float* __restrict__ out,
    float*       __restrict__ sums)      // sums[0..127]=sum, [128..255]=sumsq
{
    const int c = threadIdx.x & 127;
    const int g = threadIdx.x >> 7;      // 0..3

    float s = 0.f, q = 0.f;
    for (int r = blockIdx.x * 4 + g; r < N_OUT; r += gridDim.x * 4) {
        const float x = out[(long)r * C_OUT + c];
        s += x;
        q = fmaf(x, x, q);
    }

    __shared__ float ls[512];
    __shared__ float lq[512];
    ls[threadIdx.x] = s;
    lq[threadIdx.x] = q;
    __syncthreads();

    if (g == 0) {
        s = ls[c] + ls[128 + c] + ls[256 + c] + ls[384 + c];
        q = lq[c] + lq[128 + c] + lq[256 + c] + lq[384 + c];
        atomicAdd(&sums[c], s);
        atomicAdd(&sums[128 + c], q);
    }
}

// ---------------------------------------------------------------------------
// Kernel 3: fold stats + gamma/beta into per-channel scale/shift.
// ---------------------------------------------------------------------------
__global__ __launch_bounds__(128) void bn_finalize(
    const float* __restrict__ sums,
    const float* __restrict__ gamma,
    const float* __restrict__ beta,
    float*       __restrict__ ss)        // ss[0..127]=scale, [128..255]=shift
{
    const int c = threadIdx.x;
    const float inv_n = 1.0f / (float)N_OUT;
    const float mean  = sums[c] * inv_n;
    const float var   = sums[128 + c] * inv_n - mean * mean;
    const float sc    = gamma[c] * rsqrtf(var + BN_EPS);
    ss[c]       = sc;
    ss[128 + c] = fmaf(-mean, sc, beta[c]);
}

// ---------------------------------------------------------------------------
// Kernel 4: y = relu(x*scale + shift), in place, float4-vectorized.
// Row = 128 floats = 32 float4 -> channel base = (i&31)*4.
// ---------------------------------------------------------------------------
__global__ __launch_bounds__(256) void bn_apply(
    float*       __restrict__ out,
    const float* __restrict__ ss)
{
    const long i = (long)blockIdx.x * blockDim.x + threadIdx.x;  // float4 idx
    const long total = (long)N_OUT * C_OUT / 4;
    if (i >= total) return;

    const int c = ((int)i & 31) * 4;
    float4 v = ((const float4*)out)[i];
    v.x = fmaxf(0.f, fmaf(v.x, ss[c + 0], ss[128 + c + 0]));
    v.y = fmaxf(0.f, fmaf(v.y, ss[c + 1], ss[128 + c + 1]));
    v.z = fmaxf(0.f, fmaf(v.z, ss[c + 2], ss[128 + c + 2]));
    v.w = fmaxf(0.f, fmaf(v.w, ss[c + 3], ss[128 + c + 3]));
    ((float4*)out)[i] = v;
}

// ---------------------------------------------------------------------------
extern "C" void kernel_launch(void* const* d_in, const int* in_sizes, int n_in,
                              void* d_out, int out_size, void* d_ws, size_t ws_size,
                              hipStream_t stream)
{
    const float* feat    = (const float*)d_in[0];   // [N_IN, 64]
    const float* weight  = (const float*)d_in[1];   // [8, 64, 128]
    const float* gamma   = (const float*)d_in[2];   // [128]
    const float* beta    = (const float*)d_in[3];   // [128]
    const int*   in_idx  = (const int*)  d_in[4];   // [8, 125000]
    const int*   out_idx = (const int*)  d_in[5];   // [8, 125000]
    float* out = (float*)d_out;                     // [250000, 128]

    float* sums = (float*)d_ws;                     // 256 floats
    float* ss   = sums + 256;                       // 256 floats

    // Zero accumulator output and stats (d_out/d_ws are poisoned 0xAA).
    hipMemsetAsync(out, 0, (size_t)N_OUT * C_OUT * sizeof(float), stream);
    hipMemsetAsync(sums, 0, 256 * sizeof(float), stream);

    // 1) gather-GEMM-scatter: grid (P/4, K), 4 waves/block, 1 pair/wave.
    dim3 g1(PPAIR / 4, KOFF);
    scatter_gemm<<<g1, 256, 0, stream>>>(feat, weight, in_idx, out_idx, out);

    // 2) BN batch stats.
    bn_stats<<<256, 512, 0, stream>>>(out, sums);

    // 3) scale/shift.
    bn_finalize<<<1, 128, 0, stream>>>(sums, gamma, beta, ss);

    // 4) normalize + ReLU in place.
    const long total4 = (long)N_OUT * C_OUT / 4;
    bn_apply<<<(int)((total4 + 255) / 256), 256, 0, stream>>>(out, ss);
}

// Round 2
// 841.130 us; speedup vs baseline: 1.8280x; 1.8280x over previous
//
#include <hip/hip_runtime.h>
#include <hip/hip_fp16.h>

#define N_IN   1000000
#define N_OUT  250000
#define KOFF   8
#define PPAIR  125000
#define C_IN   64
#define C_OUT  128
#define BN_EPS 1e-5f

typedef __attribute__((ext_vector_type(8))) short short8;
typedef __attribute__((ext_vector_type(4))) float floatx4;

// float -> bf16 with round-to-nearest-even
__device__ __forceinline__ unsigned short f2bf(float x) {
    unsigned u = __float_as_uint(x);
    unsigned r = u + 0x7FFF + ((u >> 16) & 1);
    return (unsigned short)(r >> 16);
}

// ---------------------------------------------------------------------------
// Kernel 0: pack W[k][i][n] fp32 -> Wpack[k][n][i] bf16 (K-major per column),
// so B-fragments are 16B-contiguous along the K (input-channel) dim.
// 64K elements total; runs once per launch, W stays L2-resident (128 KB).
// ---------------------------------------------------------------------------
__global__ __launch_bounds__(256) void pack_w(
    const float* __restrict__ W, unsigned short* __restrict__ wp)
{
    int e = blockIdx.x * 256 + threadIdx.x;          // e < 8*64*128 = 65536
    int k = e >> 13;
    int rem = e & 8191;
    int i = rem >> 7;                                // input channel (K)
    int n = rem & 127;                               // output channel (N)
    wp[k * 8192 + n * 64 + i] = f2bf(W[e]);
}

// ---------------------------------------------------------------------------
// Kernel 1: MFMA gather-GEMM-scatter. One wave = 16 pairs x 128 channels
// via 16x mfma_f32_16x16x32_bf16 (2 K-steps x 8 N-tiles). No LDS, no syncs.
// A-frag: lane supplies pair m=lane&15, k-chunk quad*8 (+32s): 8 contiguous
//   floats from the gathered feature row, converted to bf16 in-register.
// B-frag: 16B contiguous from Wpack[k][n][*] (L1-resident).
// C/D layout (HW-verified): col(N)=lane&15, row(M)=quad*4+reg.
// Scatter: PK=1 -> packed fp16 atomics (even lanes, shfl_xor pairing) into
// fp16 accum ws; PK=0 -> fp32 atomics into d_out.
// ---------------------------------------------------------------------------
template <bool PK>
__global__ __launch_bounds__(256) void scatter_mfma(
    const float*          __restrict__ feat,
    const unsigned short* __restrict__ wpack,
    const int*            __restrict__ in_idx,
    const int*            __restrict__ out_idx,
    __half*               __restrict__ hacc,
    float*                __restrict__ facc)
{
    const int lane = threadIdx.x & 63;
    const int wave = threadIdx.x >> 6;               // 0..3
    const int quad = lane >> 4;                      // 0..3
    const int col  = lane & 15;
    const int k    = blockIdx.y;
    const int base = blockIdx.x * 64 + wave * 16;    // first pair of this wave

    // ---- A fragments (2 K-steps) ----
    const int gp_a = base + col;                     // pair this lane supplies
    const int iid  = (gp_a < PPAIR) ? in_idx[k * PPAIR + gp_a] : 0;
    const float* frow = feat + (long)iid * C_IN;

    short8 afrag[2];
#pragma unroll
    for (int s = 0; s < 2; ++s) {
        const float4 f0 = *(const float4*)(frow + s * 32 + quad * 8);
        const float4 f1 = *(const float4*)(frow + s * 32 + quad * 8 + 4);
        short8 a;
        a[0] = (short)f2bf(f0.x); a[1] = (short)f2bf(f0.y);
        a[2] = (short)f2bf(f0.z); a[3] = (short)f2bf(f0.w);
        a[4] = (short)f2bf(f1.x); a[5] = (short)f2bf(f1.y);
        a[6] = (short)f2bf(f1.z); a[7] = (short)f2bf(f1.w);
        afrag[s] = a;
    }

    // ---- B fragments: Wpack[k][n= t*16+col][ s*32 + quad*8 + 0..7 ] ----
    const unsigned short* wk = wpack + k * 8192;
    short8 bfrag[2][8];
#pragma unroll
    for (int s = 0; s < 2; ++s)
#pragma unroll
        for (int t = 0; t < 8; ++t)
            bfrag[s][t] = *(const short8*)(wk + (t * 16 + col) * 64 + s * 32 + quad * 8);

    // ---- 16 MFMAs ----
    floatx4 acc[8];
#pragma unroll
    for (int t = 0; t < 8; ++t) acc[t] = (floatx4){0.f, 0.f, 0.f, 0.f};
#pragma unroll
    for (int s = 0; s < 2; ++s)
#pragma unroll
        for (int t = 0; t < 8; ++t)
            acc[t] = __builtin_amdgcn_mfma_f32_16x16x32_bf16(
                afrag[s], bfrag[s][t], acc[t], 0, 0, 0);

    // ---- scatter ----
    int oid[4];
#pragma unroll
    for (int r = 0; r < 4; ++r) {
        const int gp = base + quad * 4 + r;          // row m = quad*4+r
        oid[r] = (gp < PPAIR) ? out_idx[k * PPAIR + gp] : -1;
    }

    if (PK) {
#pragma unroll
        for (int t = 0; t < 8; ++t)
#pragma unroll
            for (int r = 0; r < 4; ++r) {
                const float v = acc[t][r];
                const float w = __shfl_xor(v, 1, 64);    // partner channel
                if (oid[r] >= 0 && !(lane & 1)) {
                    const __half2 h = __halves2half2(__float2half(v), __float2half(w));
                    unsafeAtomicAdd((__half2*)(hacc + (long)oid[r] * C_OUT + t * 16 + col), h);
                }
            }
    } else {
#pragma unroll
        for (int t = 0; t < 8; ++t)
#pragma unroll
            for (int r = 0; r < 4; ++r)
                if (oid[r] >= 0)
                    atomicAdd(facc + (long)oid[r] * C_OUT + t * 16 + col, acc[t][r]);
    }
}

// ---------------------------------------------------------------------------
// BN stats (fp16 accum): per-channel sum / sumsq.
// ---------------------------------------------------------------------------
__global__ __launch_bounds__(256) void bn_stats_h(
    const __half* __restrict__ hacc, float* __restrict__ sums)
{
    const int c2 = threadIdx.x & 63;     // half2 column (channels 2c2, 2c2+1)
    const int g  = threadIdx.x >> 6;     // 0..3
    float s0 = 0.f, s1 = 0.f, q0 = 0.f, q1 = 0.f;
    for (int r = blockIdx.x * 4 + g; r < N_OUT; r += gridDim.x * 4) {
        const __half2 h = ((const __half2*)hacc)[(long)r * 64 + c2];
        const float2 f = __half22float2(h);
        s0 += f.x; s1 += f.y;
        q0 = fmaf(f.x, f.x, q0); q1 = fmaf(f.y, f.y, q1);
    }
    __shared__ float4 ls[256];
    ls[threadIdx.x] = make_float4(s0, s1, q0, q1);
    __syncthreads();
    if (g == 0) {
        float4 a = ls[c2], b = ls[64 + c2], c = ls[128 + c2], d = ls[192 + c2];
        atomicAdd(&sums[2 * c2],       a.x + b.x + c.x + d.x);
        atomicAdd(&sums[2 * c2 + 1],   a.y + b.y + c.y + d.y);
        atomicAdd(&sums[128 + 2 * c2],     a.z + b.z + c.z + d.z);
        atomicAdd(&sums[128 + 2 * c2 + 1], a.w + b.w + c.w + d.w);
    }
}

// BN stats (fp32 fallback, reads d_out in place)
__global__ __launch_bounds__(512) void bn_stats_f(
    const float* __restrict__ out, float* __restrict__ sums)
{
    const int c = threadIdx.x & 127;
    const int g = threadIdx.x >> 7;
    float s = 0.f, q = 0.f;
    for (int r = blockIdx.x * 4 + g; r < N_OUT; r += gridDim.x * 4) {
        const float x = out[(long)r * C_OUT + c];
        s += x; q = fmaf(x, x, q);
    }
    __shared__ float ls[512], lq[512];
    ls[threadIdx.x] = s; lq[threadIdx.x] = q;
    __syncthreads();
    if (g == 0) {
        atomicAdd(&sums[c],       ls[c] + ls[128 + c] + ls[256 + c] + ls[384 + c]);
        atomicAdd(&sums[128 + c], lq[c] + lq[128 + c] + lq[256 + c] + lq[384 + c]);
    }
}

__global__ __launch_bounds__(128) void bn_finalize(
    const float* __restrict__ sums,
    const float* __restrict__ gamma,
    const float* __restrict__ beta,
    float*       __restrict__ ss)
{
    const int c = threadIdx.x;
    const float inv_n = 1.0f / (float)N_OUT;
    const float mean  = sums[c] * inv_n;
    const float var   = sums[128 + c] * inv_n - mean * mean;
    const float sc    = gamma[c] * rsqrtf(var + BN_EPS);
    ss[c]       = sc;
    ss[128 + c] = fmaf(-mean, sc, beta[c]);
}

// BN apply (fp16 accum -> fp32 out)
__global__ __launch_bounds__(256) void bn_apply_h(
    const __half* __restrict__ hacc,
    const float*  __restrict__ ss,
    float*        __restrict__ out)
{
    const long j = (long)blockIdx.x * 256 + threadIdx.x;   // float4 index
    const __half2 h0 = ((const __half2*)hacc)[j * 2];
    const __half2 h1 = ((const __half2*)hacc)[j * 2 + 1];
    const float2 f0 = __half22float2(h0);
    const float2 f1 = __half22float2(h1);
    const int c = ((int)j & 31) * 4;
    float4 v;
    v.x = fmaxf(0.f, fmaf(f0.x, ss[c + 0], ss[128 + c + 0]));
    v.y = fmaxf(0.f, fmaf(f0.y, ss[c + 1], ss[128 + c + 1]));
    v.z = fmaxf(0.f, fmaf(f1.x, ss[c + 2], ss[128 + c + 2]));
    v.w = fmaxf(0.f, fmaf(f1.y, ss[c + 3], ss[128 + c + 3]));
    ((float4*)out)[j] = v;
}

// BN apply (fp32 in place, fallback)
__global__ __launch_bounds__(256) void bn_apply_f(
    float* __restrict__ out, const float* __restrict__ ss)
{
    const long j = (long)blockIdx.x * 256 + threadIdx.x;
    const int c = ((int)j & 31) * 4;
    float4 v = ((const float4*)out)[j];
    v.x = fmaxf(0.f, fmaf(v.x, ss[c + 0], ss[128 + c + 0]));
    v.y = fmaxf(0.f, fmaf(v.y, ss[c + 1], ss[128 + c + 1]));
    v.z = fmaxf(0.f, fmaf(v.z, ss[c + 2], ss[128 + c + 2]));
    v.w = fmaxf(0.f, fmaf(v.w, ss[c + 3], ss[128 + c + 3]));
    ((float4*)out)[j] = v;
}

// ---------------------------------------------------------------------------
extern "C" void kernel_launch(void* const* d_in, const int* in_sizes, int n_in,
                              void* d_out, int out_size, void* d_ws, size_t ws_size,
                              hipStream_t stream)
{
    const float* feat    = (const float*)d_in[0];
    const float* weight  = (const float*)d_in[1];
    const float* gamma   = (const float*)d_in[2];
    const float* beta    = (const float*)d_in[3];
    const int*   in_idx  = (const int*)  d_in[4];
    const int*   out_idx = (const int*)  d_in[5];
    float* out = (float*)d_out;

    const size_t HACC_BYTES = (size_t)N_OUT * C_OUT * sizeof(__half); // 64 MB
    const size_t BIG_NEED   = HACC_BYTES + 1024 + 131072 + 1024;
    const bool   big        = ws_size >= BIG_NEED;

    char* wsb = (char*)d_ws;
    __half* hacc;
    float* sums;
    unsigned short* wpack;
    if (big) {
        hacc  = (__half*)wsb;
        sums  = (float*)(wsb + HACC_BYTES);
        wpack = (unsigned short*)(wsb + HACC_BYTES + 1024);
    } else {
        hacc  = nullptr;
        sums  = (float*)wsb;
        wpack = (unsigned short*)(wsb + 1024);
    }
    float* ss = sums + 256;   // 256 floats of scale/shift after sums block? no:
    // keep ss in its own spot right after sums (sums uses 256 floats = 1KB? 256*4=1024B).
    // sums occupies [0,1024); put ss inside same 1KB? Need 256 floats = 1024B more.
    // Use wpack area end for ss:
    ss = (float*)((char*)wpack + 131072);

    // zero accumulators + stats
    if (big) {
        hipMemsetAsync(hacc, 0, HACC_BYTES, stream);
    } else {
        hipMemsetAsync(out, 0, (size_t)N_OUT * C_OUT * sizeof(float), stream);
    }
    hipMemsetAsync(sums, 0, 256 * sizeof(float), stream);

    // 0) pack weights to bf16 K-major
    pack_w<<<256, 256, 0, stream>>>(weight, wpack);

    // 1) MFMA gather-GEMM-scatter
    dim3 g1((PPAIR + 63) / 64, KOFF);
    if (big)
        scatter_mfma<true><<<g1, 256, 0, stream>>>(feat, wpack, in_idx, out_idx, hacc, out);
    else
        scatter_mfma<false><<<g1, 256, 0, stream>>>(feat, wpack, in_idx, out_idx, hacc, out);

    // 2) BN stats
    if (big) bn_stats_h<<<256, 256, 0, stream>>>(hacc, sums);
    else     bn_stats_f<<<256, 512, 0, stream>>>(out, sums);

    // 3) scale/shift
    bn_finalize<<<1, 128, 0, stream>>>(sums, gamma, beta, ss);

    // 4) normalize + ReLU
    const int nblk = (int)((long)N_OUT * C_OUT / 4 / 256);   // 31250
    if (big) bn_apply_h<<<nblk, 256, 0, stream>>>(hacc, ss, out);
    else     bn_apply_f<<<nblk, 256, 0, stream>>>(out, ss);
}